// Round 1
// baseline (979.619 us; speedup 1.0000x reference)
//
#include <hip/hip_runtime.h>
#include <math.h>

// Problem constants (fixed by reference): N=4096, L_V=64, H=512, D=256
#define NN      4096
#define LV      64
#define HH      512
#define DD      256
#define KTOT    1280            // 3*D (x) + H (cur_h) combined K
#define BM      8               // n-rows per GEMM block
#define G_GEMM  (NN / BM)       // 512 GEMM blocks
#define G_COPY  4096            // copy blocks
#define NTHREADS 256
#define COPY_ITERS 32           // 4096 blk * 256 thr * 32 it = 33,554,432 float4 = N*LV*HH/4

typedef float f4 __attribute__((ext_vector_type(4)));

__global__ __launch_bounds__(NTHREADS)
void coord_mem_kernel(const float* __restrict__ memory,
                      const int*   __restrict__ veh_idx,
                      const float* __restrict__ veh_repr,
                      const float* __restrict__ cust_repr,
                      const float* __restrict__ edge_emb,
                      const float* __restrict__ W_in,
                      const float* __restrict__ b_in,
                      const float* __restrict__ W_h,
                      const float* __restrict__ b_h,
                      float* __restrict__ out)
{
    __shared__ float xs[BM][KTOT];   // 8 * 1280 * 4B = 40 KB
    const int tid = threadIdx.x;
    const int bid = blockIdx.x;

    if (bid < G_GEMM) {
        // ---------------- GEMM + tanh + scatter path ----------------
        const int n0 = bid * BM;

        // Stage concatenated input rows [veh|cust|edge|cur_h] into LDS.
        // 8 rows * 320 float4 = 2560 chunks over 256 threads.
        for (int i = tid; i < BM * (KTOT / 4); i += NTHREADS) {
            const int r  = i / (KTOT / 4);
            const int c4 = i - r * (KTOT / 4);
            const int k  = c4 * 4;
            const int n  = n0 + r;
            f4 v;
            if (k < 256) {
                v = *(const f4*)(veh_repr + (size_t)n * DD + k);
            } else if (k < 512) {
                v = *(const f4*)(cust_repr + (size_t)n * DD + (k - 256));
            } else if (k < 768) {
                v = *(const f4*)(edge_emb + (size_t)n * DD + (k - 512));
            } else {
                const int veh = veh_idx[n];
                v = *(const f4*)(memory + ((size_t)n * LV + veh) * HH + (k - 768));
            }
            *(f4*)(&xs[r][k]) = v;
        }
        __syncthreads();

        const int c0 = tid << 1;           // 2 contiguous output cols per thread
        float acc0[BM], acc1[BM];
        #pragma unroll
        for (int r = 0; r < BM; ++r) { acc0[r] = 0.f; acc1[r] = 0.f; }

        // K-part 1: x @ W_in  (k = 0..767)
        for (int k = 0; k < 768; k += 4) {
            const float* wb = W_in + (size_t)k * HH + c0;
            const float2 w0 = *(const float2*)(wb);
            const float2 w1 = *(const float2*)(wb + HH);
            const float2 w2 = *(const float2*)(wb + 2 * HH);
            const float2 w3 = *(const float2*)(wb + 3 * HH);
            #pragma unroll
            for (int r = 0; r < BM; ++r) {
                const f4 xv = *(const f4*)(&xs[r][k]);   // lane-uniform -> LDS broadcast
                acc0[r] += xv.x * w0.x; acc1[r] += xv.x * w0.y;
                acc0[r] += xv.y * w1.x; acc1[r] += xv.y * w1.y;
                acc0[r] += xv.z * w2.x; acc1[r] += xv.z * w2.y;
                acc0[r] += xv.w * w3.x; acc1[r] += xv.w * w3.y;
            }
        }
        // K-part 2: cur_h @ W_h  (k = 0..511, xs cols 768..1279)
        for (int k = 0; k < 512; k += 4) {
            const float* wb = W_h + (size_t)k * HH + c0;
            const float2 w0 = *(const float2*)(wb);
            const float2 w1 = *(const float2*)(wb + HH);
            const float2 w2 = *(const float2*)(wb + 2 * HH);
            const float2 w3 = *(const float2*)(wb + 3 * HH);
            #pragma unroll
            for (int r = 0; r < BM; ++r) {
                const f4 xv = *(const f4*)(&xs[r][768 + k]);
                acc0[r] += xv.x * w0.x; acc1[r] += xv.x * w0.y;
                acc0[r] += xv.y * w1.x; acc1[r] += xv.y * w1.y;
                acc0[r] += xv.z * w2.x; acc1[r] += xv.z * w2.y;
                acc0[r] += xv.w * w3.x; acc1[r] += xv.w * w3.y;
            }
        }

        const float bb0 = b_in[c0] + b_h[c0];
        const float bb1 = b_in[c0 + 1] + b_h[c0 + 1];
        #pragma unroll
        for (int r = 0; r < BM; ++r) {
            const int n = n0 + r;
            const int veh = veh_idx[n];
            float* orow = out + ((size_t)n * LV + veh) * HH;
            float2 o;
            o.x = tanhf(acc0[r] + bb0);
            o.y = tanhf(acc1[r] + bb1);
            *(float2*)(orow + c0) = o;
        }
    } else {
        // ---------------- streaming copy path (skips updated rows) ----------------
        const int cb = bid - G_GEMM;
        const f4* __restrict__ in4 = (const f4*)memory;
        f4* __restrict__ out4 = (f4*)out;
        const size_t stride = (size_t)G_COPY * NTHREADS;
        size_t i = (size_t)cb * NTHREADS + tid;
        #pragma unroll 4
        for (int j = 0; j < COPY_ITERS; ++j, i += stride) {
            // i is a float4 index: 8192 f4 per n (2^13), 128 f4 per l-row (2^7)
            const int n = (int)(i >> 13);
            const int l = ((int)(i >> 7)) & 63;
            if (l != veh_idx[n]) {           // wave-uniform branch (wave spans half a row)
                const f4 v = __builtin_nontemporal_load(in4 + i);
                __builtin_nontemporal_store(v, out4 + i);
            }
        }
    }
}

extern "C" void kernel_launch(void* const* d_in, const int* in_sizes, int n_in,
                              void* d_out, int out_size, void* d_ws, size_t ws_size,
                              hipStream_t stream) {
    const float* memory    = (const float*)d_in[0];
    const int*   veh_idx   = (const int*)d_in[1];
    const float* veh_repr  = (const float*)d_in[2];
    const float* cust_repr = (const float*)d_in[3];
    const float* edge_emb  = (const float*)d_in[4];
    const float* W_in      = (const float*)d_in[5];
    const float* b_in      = (const float*)d_in[6];
    const float* W_h       = (const float*)d_in[7];
    const float* b_h       = (const float*)d_in[8];
    float* out = (float*)d_out;

    dim3 grid(G_GEMM + G_COPY);
    dim3 block(NTHREADS);
    hipLaunchKernelGGL(coord_mem_kernel, grid, block, 0, stream,
                       memory, veh_idx, veh_repr, cust_repr, edge_emb,
                       W_in, b_in, W_h, b_h, out);
}